// Round 5
// baseline (603.503 us; speedup 1.0000x reference)
//
#include <hip/hip_runtime.h>

#define N_ROWS   131072
#define D_IN     512
#define D_H      128
#define K_CODES  256
#define NT       512          // 8 waves, 16 rows each
#define PNT      256          // prep/finalize block size (layout-coupled, keep 256)
#define RPB      128          // rows per block
#define NBLK     (N_ROWS / RPB)
#define SA       136          // s_A row stride in bf16 elems (272 B, breaks power-of-2)
#define NROUND   28           // 28 x 16KB B rounds = whole wsb, consumed linearly

typedef __attribute__((ext_vector_type(8))) short bf16x8;
typedef __attribute__((ext_vector_type(4))) float f32x4;

__device__ inline unsigned short f2bf(float f) {
    unsigned u = __float_as_uint(f);
    return (unsigned short)((u + 0x7FFFu + ((u >> 16) & 1u)) >> 16);
}
__device__ inline ushort4 f2bf4(float4 v) {
    return make_ushort4(f2bf(v.x), f2bf(v.y), f2bf(v.z), f2bf(v.w));
}
__device__ inline bf16x8 f2bf8(float4 a, float4 b) {
    bf16x8 r;
    r[0] = (short)f2bf(a.x); r[1] = (short)f2bf(a.y); r[2] = (short)f2bf(a.z); r[3] = (short)f2bf(a.w);
    r[4] = (short)f2bf(b.x); r[5] = (short)f2bf(b.y); r[6] = (short)f2bf(b.z); r[7] = (short)f2bf(b.w);
    return r;
}

// async global->LDS DMA, 16B per lane; LDS dest is wave-uniform base + lane*16
typedef const __attribute__((address_space(1))) void* gv_t;
typedef __attribute__((address_space(3))) void* lv_t;
__device__ __forceinline__ void gll16(const unsigned short* g, unsigned short* l) {
    __builtin_amdgcn_global_load_lds((gv_t)g, (lv_t)l, 16, 0, 0);
}

// ---------------- prep: reorder weights/codebooks into MFMA B-fragment order ----------------
// B-fragment order: frag(ct,ks) is 64 lanes x 8 bf16, lane = qd*16+nn holds
// B[n = ct*16+nn][k = ks*32 + qd*8 + j], j=0..7.  One 32KB "round" = 8 ct x 4 ks.
// wsb layout (ushorts): [0..65535] Wenc rounds kc=0..3 | [65536..163839] cb (t,half) rounds | [163840..229375] Wdec rounds c=0..3
__global__ void rqvae_prep(const float* __restrict__ Wenc,
                           const float* __restrict__ Wdec,
                           const float* __restrict__ cb0,
                           const float* __restrict__ cb1,
                           const float* __restrict__ cb2,
                           unsigned short* __restrict__ wsb,
                           float* __restrict__ norms)
{
    const int tid = threadIdx.x;
    const int b = blockIdx.x;
    const float* cbs[3] = {cb0, cb1, cb2};
    if (b < 112) {
        const int g = b * 256 + tid;            // ushort8 group id, 0..28671
        const int lane = g & 63, ks = (g >> 6) & 3, ct = (g >> 8) & 7;
        const int nn = lane & 15, qd = lane >> 4;
        const float* src;
        if (g < 8192) {                         // Wenc: kc = g>>11
            const int kc = g >> 11;
            src = Wenc + (ct * 16 + nn) * D_IN + kc * 128 + ks * 32 + qd * 8;
        } else if (g < 20480) {                 // cb: t = (g-8192)>>12, half = bit 11
            const int r = g - 8192;
            const int t = r >> 12, half = (r >> 11) & 1;
            src = cbs[t] + (long)(half * 128 + ct * 16 + nn) * D_H + ks * 32 + qd * 8;
        } else {                                // Wdec: c = (g-20480)>>11
            const int r = g - 20480;
            const int c = r >> 11;
            src = Wdec + (long)(c * 128 + ct * 16 + nn) * D_H + ks * 32 + qd * 8;
        }
        float4 v0 = *(const float4*)(src);
        float4 v1 = *(const float4*)(src + 4);
        *(ushort4*)(wsb + (long)g * 8)     = f2bf4(v0);
        *(ushort4*)(wsb + (long)g * 8 + 4) = f2bf4(v1);
    } else {
        const int t = b - 112;                  // norm blocks: one code per thread
        const float4* r = (const float4*)(cbs[t] + (long)tid * D_H);
        float s = 0.f;
        #pragma unroll
        for (int d = 0; d < 32; ++d) { float4 v = r[d]; s += v.x*v.x + v.y*v.y + v.z*v.z + v.w*v.w; }
        norms[t * K_CODES + tid] = -0.5f * s;
    }
}

// ---------------- main ----------------
// Occupancy-targeted geometry: 8 waves x 16 rows (was 4 x 32). Every prior round
// sat at 2 waves/SIMD because rem[2][8]+res[2][8] = 128 acc regs + ~116 VGPR ~= 244
// unified regs. Now: rem[8] = 32 acc regs; res is NOT kept -- the 3x4 winning code
// indices are saved (12 VGPRs) and res is re-gathered from L2 at phase-3 entry
// (bit-identical add order). launch_bounds(512,4) pins <=128 regs -> 4 waves/SIMD,
// 16 waves/CU, same 70656B LDS (2 blocks/CU), same 28-round DMA dbuf pipeline.
// Spill tripwire: WRITE_SIZE must stay ~0.3MB.
__global__ __launch_bounds__(NT, 4) void rqvae_main(
    const float* __restrict__ emb,
    const float* __restrict__ cb0,
    const float* __restrict__ cb1,
    const float* __restrict__ cb2,
    const unsigned short* __restrict__ wsb,
    const float* __restrict__ norms,
    float* __restrict__ acc_rq,
    float* __restrict__ acc_recon,
    int* __restrict__ used)
{
    __shared__ unsigned short s_A[RPB * SA];   // 34816 B: latent/rem/restored, wave-private rows
    __shared__ unsigned short s_B[2][8192];    // 32768 B: double-buffered 16KB B rounds
    __shared__ float s_cn[3 * K_CODES];        // 3072 B  -> total 70656 B, 2 blocks/CU

    const int tid  = threadIdx.x;
    const int wv   = tid >> 6;                 // 0..7
    const int lane = tid & 63;
    const int nn   = lane & 15;
    const int qd   = lane >> 4;
    const int wrow = wv * 16;                  // this wave's 16 rows in the block
    const long blkRow = (long)blockIdx.x * RPB;
    const float* cbs[3] = {cb0, cb1, cb2};

    for (int i = tid; i < 3 * K_CODES; i += NT) s_cn[i] = norms[i];

#define STAGE(r, buf) do {                                                      \
        const unsigned short* _s = wsb + (r) * 8192;                            \
        _Pragma("unroll")                                                       \
        for (int _i = 0; _i < 2; ++_i)                                          \
            gll16(_s + _i * 4096 + wv * 512 + lane * 8,                         \
                  &s_B[buf][_i * 4096 + wv * 512]);                             \
    } while (0)

    STAGE(0, 0);
    __syncthreads();                           // round-0 data + s_cn visible
    int cur = 0;

    f32x4 rem[8];
    #pragma unroll
    for (int ct = 0; ct < 8; ++ct) rem[ct] = {0.f,0.f,0.f,0.f};

    // ---- Phase 1: latent = emb @ Wenc^T; rounds 0..7, A direct global->reg ----
    #pragma unroll 1
    for (int kc = 0; kc < 4; ++kc) {
        STAGE(kc * 2 + 1, cur ^ 1);            // prefetch next round before the A-load stall
        bf16x8 af[4];
        {
            const float* arow = emb + (blkRow + wrow + nn) * D_IN + kc * 128 + qd * 8;
            #pragma unroll
            for (int ks = 0; ks < 4; ++ks)
                af[ks] = f2bf8(*(const float4*)(arow + ks * 32), *(const float4*)(arow + ks * 32 + 4));
        }
        // round kc*2: latent cols 0..63 (ct = 0..3)
        __builtin_amdgcn_s_setprio(1);
        #pragma unroll
        for (int ctc = 0; ctc < 4; ++ctc)
            #pragma unroll
            for (int ks = 0; ks < 4; ++ks) {
                bf16x8 bf = *(const bf16x8*)&s_B[cur][(ctc * 4 + ks) * 512 + lane * 8];
                rem[ctc] = __builtin_amdgcn_mfma_f32_16x16x32_bf16(af[ks], bf, rem[ctc], 0, 0, 0);
            }
        __builtin_amdgcn_s_setprio(0);
        __syncthreads(); cur ^= 1;
        STAGE(kc * 2 + 2, cur ^ 1);            // kc=3 stages round 8 = first phase-2 round
        // round kc*2+1: latent cols 64..127 (ct = 4..7)
        __builtin_amdgcn_s_setprio(1);
        #pragma unroll
        for (int ctc = 0; ctc < 4; ++ctc)
            #pragma unroll
            for (int ks = 0; ks < 4; ++ks) {
                bf16x8 bf = *(const bf16x8*)&s_B[cur][(ctc * 4 + ks) * 512 + lane * 8];
                rem[4 + ctc] = __builtin_amdgcn_mfma_f32_16x16x32_bf16(af[ks], bf, rem[4 + ctc], 0, 0, 0);
            }
        __builtin_amdgcn_s_setprio(0);
        __syncthreads(); cur ^= 1;
    }

    // latent -> s_A bf16 (wave-private rows)
    #pragma unroll
    for (int ct = 0; ct < 8; ++ct)
        #pragma unroll
        for (int e = 0; e < 4; ++e)
            s_A[(wrow + qd * 4 + e) * SA + ct * 16 + nn] = f2bf(rem[ct][e]);

    // ---- Phase 2: three RQ stages; rounds 8..19 (4 x 16KB per stage) ----
    float local_rq = 0.f;
    int bis[3][4];                             // winning code per stage per row-quad elem
    #pragma unroll 1
    for (int t = 0; t < 3; ++t) {
        const float* __restrict__ cb = cbs[t];
        float bv[4]; int bi[4];
        #pragma unroll
        for (int e = 0; e < 4; ++e) { bv[e] = -3.402823466e38f; bi[e] = 0; }

        bf16x8 af[4];
        #pragma unroll
        for (int ks = 0; ks < 4; ++ks)
            af[ks] = *(const bf16x8*)&s_A[(wrow + nn) * SA + ks * 32 + qd * 8];

        #pragma unroll 1
        for (int rl = 0; rl < 4; ++rl) {
            STAGE(8 + t * 4 + rl + 1, cur ^ 1);            // <= round 20, always valid
            __builtin_amdgcn_s_setprio(1);
            #pragma unroll
            for (int ctc = 0; ctc < 4; ++ctc) {
                f32x4 s0 = {0.f,0.f,0.f,0.f};
                #pragma unroll
                for (int ks = 0; ks < 4; ++ks) {
                    bf16x8 bf = *(const bf16x8*)&s_B[cur][(ctc * 4 + ks) * 512 + lane * 8];
                    s0 = __builtin_amdgcn_mfma_f32_16x16x32_bf16(af[ks], bf, s0, 0, 0, 0);
                }
                const int code = rl * 64 + ctc * 16 + nn;
                const float cn = s_cn[t * K_CODES + code];
                #pragma unroll
                for (int e = 0; e < 4; ++e) {
                    const float v0 = s0[e] + cn;
                    if (v0 > bv[e] || (v0 == bv[e] && code < bi[e])) { bv[e] = v0; bi[e] = code; }
                }
            }
            __builtin_amdgcn_s_setprio(0);
            __syncthreads(); cur ^= 1;
        }
        // argmax over the 16 nn-lanes of each quad (tie -> lowest index)
        #pragma unroll
        for (int e = 0; e < 4; ++e) {
            float v = bv[e]; int i0 = bi[e];
            #pragma unroll
            for (int m = 8; m >= 1; m >>= 1) {
                const float ov = __shfl_xor(v, m);
                const int   oi = __shfl_xor(i0, m);
                if (ov > v || (ov == v && oi < i0)) { v = ov; i0 = oi; }
            }
            bi[e] = i0;
            bis[t][e] = i0;
            if (nn == 0) used[t * K_CODES + i0] = 1;
        }
        // update rem with fp32 codebook rows (res NOT kept -- re-gathered in phase 3)
        #pragma unroll
        for (int ct = 0; ct < 8; ++ct)
            #pragma unroll
            for (int e = 0; e < 4; ++e) {
                const float c = cb[(long)bi[e] * D_H + ct * 16 + nn];
                const float rr = rem[ct][e] - c;
                rem[ct][e] = rr;
                local_rq += rr * rr;
                if (t < 2)
                    s_A[(wrow + qd * 4 + e) * SA + ct * 16 + nn] = f2bf(rr);
            }
    }

    // restored = cb0[i0]+cb1[i1]+cb2[i2] re-gathered (same add order as res += c) -> s_A bf16
    #pragma unroll
    for (int ct = 0; ct < 8; ++ct)
        #pragma unroll
        for (int e = 0; e < 4; ++e) {
            const int co = ct * 16 + nn;
            const float r = cbs[0][(long)bis[0][e] * D_H + co]
                          + cbs[1][(long)bis[1][e] * D_H + co]
                          + cbs[2][(long)bis[2][e] * D_H + co];
            s_A[(wrow + qd * 4 + e) * SA + co] = f2bf(r);
        }

    // ---- Phase 3: recon = restored @ Wdec^T; rounds 20..27, diff vs fp32 emb ----
    float local_rec = 0.f;
    {
        bf16x8 af[4];
        #pragma unroll
        for (int ks = 0; ks < 4; ++ks)
            af[ks] = *(const bf16x8*)&s_A[(wrow + nn) * SA + ks * 32 + qd * 8];
        #pragma unroll 1
        for (int rl = 0; rl < 8; ++rl) {
            if (rl < 7) STAGE(21 + rl, cur ^ 1);
            __builtin_amdgcn_s_setprio(1);
            #pragma unroll
            for (int ctc = 0; ctc < 4; ++ctc) {
                f32x4 r0 = {0.f,0.f,0.f,0.f};
                #pragma unroll
                for (int ks = 0; ks < 4; ++ks) {
                    bf16x8 bf = *(const bf16x8*)&s_B[cur][(ctc * 4 + ks) * 512 + lane * 8];
                    r0 = __builtin_amdgcn_mfma_f32_16x16x32_bf16(af[ks], bf, r0, 0, 0, 0);
                }
                const int col = rl * 64 + ctc * 16 + nn;
                #pragma unroll
                for (int e = 0; e < 4; ++e) {
                    const float e0 = emb[(blkRow + wrow + qd * 4 + e) * D_IN + col];
                    const float d0 = r0[e] - e0;
                    local_rec += d0 * d0;
                }
            }
            __builtin_amdgcn_s_setprio(0);
            if (rl < 7) __syncthreads();
            cur ^= 1;
        }
    }
#undef STAGE

    // ---- wave shuffle reduce, one atomic pair per wave ----
    float r1 = local_rq, r2 = local_rec;
    #pragma unroll
    for (int m = 32; m >= 1; m >>= 1) { r1 += __shfl_xor(r1, m); r2 += __shfl_xor(r2, m); }
    if (lane == 0) { atomicAdd(acc_rq, r1); atomicAdd(acc_recon, r2); }
}

__global__ void rqvae_finalize(const float* __restrict__ acc,
                               const int* __restrict__ used,
                               float* __restrict__ out)
{
    __shared__ int s_sum[4];
    const int tid = threadIdx.x;
    for (int t = 0; t < 3; ++t) {
        int v = (used[t * K_CODES + tid] != 0) ? 1 : 0;
        #pragma unroll
        for (int off = 32; off >= 1; off >>= 1) v += __shfl_down(v, off);
        if ((tid & 63) == 0) s_sum[tid >> 6] = v;
        __syncthreads();
        if (tid == 0) out[3 + t] = (float)(s_sum[0] + s_sum[1] + s_sum[2] + s_sum[3]);
        __syncthreads();
    }
    if (tid == 0) {
        const float rq    = 1.25f * acc[0] / ((float)N_ROWS * 128.0f);
        const float recon =         acc[1] / ((float)N_ROWS * 512.0f);
        out[0] = recon + rq;
        out[1] = recon;
        out[2] = rq;
    }
}

extern "C" void kernel_launch(void* const* d_in, const int* in_sizes, int n_in,
                              void* d_out, int out_size, void* d_ws, size_t ws_size,
                              hipStream_t stream) {
    const float* emb  = (const float*)d_in[0];
    const float* Wenc = (const float*)d_in[1];
    const float* Wdec = (const float*)d_in[2];
    const float* cb0  = (const float*)d_in[3];
    const float* cb1  = (const float*)d_in[4];
    const float* cb2  = (const float*)d_in[5];

    // workspace layout (bytes): [0] 2 f32 acc | [64] 768 int used | [3200] 768 f32 norms | [8192] 448KB bf16 frags
    float* ws_f  = (float*)d_ws;
    int*   used  = (int*)((char*)d_ws + 64);
    float* norms = (float*)((char*)d_ws + 3200);
    unsigned short* wsb = (unsigned short*)((char*)d_ws + 8192);

    hipMemsetAsync(d_ws, 0, 3200, stream);
    rqvae_prep<<<115, PNT, 0, stream>>>(Wenc, Wdec, cb0, cb1, cb2, wsb, norms);
    rqvae_main<<<NBLK, NT, 0, stream>>>(emb, cb0, cb1, cb2, wsb, norms,
                                        ws_f + 0, ws_f + 1, used);
    rqvae_finalize<<<1, PNT, 0, stream>>>(ws_f, used, (float*)d_out);
}